// Round 14
// baseline (448.480 us; speedup 1.0000x reference)
//
#include <hip/hip_runtime.h>
#include <hip/hip_bf16.h>

using bf16x8 = __attribute__((ext_vector_type(8))) short;
using f32x4  = __attribute__((ext_vector_type(4))) float;

__device__ __forceinline__ float b2f(unsigned short u) {
  union { unsigned int i; float f; } c;
  c.i = ((unsigned int)u) << 16;
  return c.f;
}
__device__ __forceinline__ unsigned short f2b(float f) {
  union { float f; unsigned int i; } c;
  c.f = f;
  unsigned int x = c.i;
  unsigned int r = x + 0x7fffu + ((x >> 16) & 1u);  // RNE
  return (unsigned short)(r >> 16);
}

static constexpr int BCAP = 10240;
static constexpr int NBAGG = 1280;

// ---------------- CSR build: bucketed two-phase ----------------
__global__ __launch_bounds__(256) void k_part(const int* __restrict__ src,
                                              const int* __restrict__ dst,
                                              int* __restrict__ bcnt,
                                              unsigned int* __restrict__ barr,
                                              int e, int nbuk) {
  __shared__ int hist[256];
  __shared__ int base[256];
  __shared__ int h2[256];
  int t = threadIdx.x;
  hist[t] = 0;
  h2[t] = 0;
  __syncthreads();
  int e0 = blockIdx.x * 2048;
  int ms[8], md[8];
#pragma unroll
  for (int i = 0; i < 8; ++i) {
    int idx = e0 + i * 256 + t;
    if (idx < e) {
      ms[i] = src[idx];
      md[i] = dst[idx];
      atomicAdd(&hist[md[i] >> 9], 1);
    } else {
      md[i] = -1;
    }
  }
  __syncthreads();
  if (t < nbuk && hist[t] > 0) base[t] = atomicAdd(&bcnt[t], hist[t]);
  __syncthreads();
#pragma unroll
  for (int i = 0; i < 8; ++i) {
    if (md[i] >= 0) {
      int b = md[i] >> 9;
      int r = atomicAdd(&h2[b], 1);
      int pos = base[b] + r;
      if (pos < BCAP)
        barr[(size_t)b * BCAP + pos] =
            (unsigned int)ms[i] | ((unsigned int)(md[i] & 511) << 17);
    }
  }
}

__global__ __launch_bounds__(512) void k_bdeg(const int* __restrict__ bcnt,
                                              const unsigned int* __restrict__ barr,
                                              int* __restrict__ deg, int n) {
  __shared__ int cnt[512];
  int t = threadIdx.x;
  int b = blockIdx.x;
  cnt[t] = 0;
  __syncthreads();
  int c = bcnt[b];
  if (c > BCAP) c = BCAP;
  for (int i = t; i < c; i += 512)
    atomicAdd(&cnt[barr[(size_t)b * BCAP + i] >> 17], 1);
  __syncthreads();
  int node = b * 512 + t;
  if (node < n) deg[node] = cnt[t];
}

__global__ __launch_bounds__(256) void k_scan1(const int* __restrict__ deg,
                                               int* __restrict__ rs,
                                               int* __restrict__ bsum, int n) {
  __shared__ int s[256];
  int t = threadIdx.x;
  int i = blockIdx.x * 256 + t;
  int v = (i < n) ? deg[i] : 0;
  s[t] = v;
  __syncthreads();
  for (int off = 1; off < 256; off <<= 1) {
    int u = (t >= off) ? s[t - off] : 0;
    __syncthreads();
    s[t] += u;
    __syncthreads();
  }
  if (i < n) rs[i] = s[t] - v;
  if (t == 255) bsum[blockIdx.x] = s[255];
}

__global__ __launch_bounds__(512) void k_scan2(const int* __restrict__ bsum,
                                               int* __restrict__ boff, int nb) {
  __shared__ int s[512];
  int t = threadIdx.x;
  int v = (t < nb) ? bsum[t] : 0;
  s[t] = v;
  __syncthreads();
  for (int off = 1; off < 512; off <<= 1) {
    int u = (t >= off) ? s[t - off] : 0;
    __syncthreads();
    s[t] += u;
    __syncthreads();
  }
  if (t < nb) boff[t] = s[t] - v;
}

__global__ __launch_bounds__(256) void k_scan3(int* __restrict__ rs,
                                               const int* __restrict__ boff,
                                               int n, int e) {
  int i = blockIdx.x * blockDim.x + threadIdx.x;
  if (i < n) rs[i] = rs[i] + boff[i >> 8];
  if (i == 0) rs[n] = e;
}

__global__ __launch_bounds__(512) void k_place(const int* __restrict__ bcnt,
                                               const unsigned int* __restrict__ barr,
                                               const int* __restrict__ rs,
                                               int* __restrict__ csr, int n) {
  __shared__ int cnt[512];
  __shared__ int basep[512];
  int t = threadIdx.x;
  int b = blockIdx.x;
  int node = b * 512 + t;
  basep[t] = (node < n) ? rs[node] : 0;
  cnt[t] = 0;
  __syncthreads();
  int c = bcnt[b];
  if (c > BCAP) c = BCAP;
  for (int i = t; i < c; i += 512) {
    unsigned int v = barr[(size_t)b * BCAP + i];
    int loc = v >> 17;
    int r = atomicAdd(&cnt[loc], 1);
    csr[basep[loc] + r] = (int)(v & 0x1FFFFu);
  }
}

// ------------- all-layer weight transpose+convert: WT[n][k] = bf16(W[k][n]) -------------
__global__ __launch_bounds__(256) void k_wt_all(
    const float* __restrict__ Wl0, const float* __restrict__ Wr0,
    const float* __restrict__ Wl1, const float* __restrict__ Wr1,
    const float* __restrict__ Wl2, const float* __restrict__ Wr2,
    unsigned short* __restrict__ WT) {
  int idx = blockIdx.x * 256 + threadIdx.x;  // 0..81919
  if (idx >= 81920) return;
  int layer = idx >> 15;
  int r = idx & 32767;
  const float *Wl, *Wr;
  int DOUT;
  if (layer == 0) { Wl = Wl0; Wr = Wr0; DOUT = 128; }
  else if (layer == 1) { Wl = Wl1; Wr = Wr1; DOUT = 128; }
  else { Wl = Wl2; Wr = Wr2; DOUT = 64; }
  int nn = r >> 7, k = r & 127;
  float v = (nn < DOUT) ? Wl[(size_t)k * DOUT + nn]
                        : Wr[(size_t)k * DOUT + (nn - DOUT)];
  WT[idx] = f2b(v);
}

// --------- MFMA dual GEMM with fused input BN+ReLU: ---------
// Xeff = FUSE ? relu(BN(Xf)) : Xf;  T16 = bf16(Xeff@Wl) ; H = Xeff@Wr + b
template <int NW, bool FUSE>
__global__ __launch_bounds__(256) void k_gemm(
    const float* __restrict__ Xf, const unsigned short* __restrict__ WT,
    const float* __restrict__ bias, const float* __restrict__ bns,
    const float* __restrict__ gamma, const float* __restrict__ beta,
    unsigned short* __restrict__ T16, float* __restrict__ H, int n) {
  constexpr int DOUT = NW / 2;
  constexpr int NT = NW / 16;
  constexpr int WS_BYTES = NW * 256;
  constexpr int EPR = NW + 4;
  constexpr int EPI_BYTES = 64 * EPR * 4;
  constexpr int SMEM_BYTES = (WS_BYTES > EPI_BYTES ? WS_BYTES : EPI_BYTES);
  __shared__ __align__(16) char smem[SMEM_BYTES];
  __shared__ float scsh[256];

  int t = threadIdx.x;
  int w = t >> 6;
  int l = t & 63;
  int lg = l >> 4;
  int ll = l & 15;
  int blk = blockIdx.x;
  int row16 = blk * 64 + w * 16;

  if constexpr (FUSE) {
    if (t < 128) {
      float invn = 1.0f / (float)n;
      float m = bns[t] * invn;
      float var = bns[128 + t] * invn - m * m;
      float sc = gamma[t] * rsqrtf(var + 1e-5f);
      scsh[t] = sc;
      scsh[128 + t] = beta[t] - m * sc;
    }
    __syncthreads();
  }

  int row = row16 + ll;
  bool valid = row < n;
  const float* xrow = Xf + (size_t)row * 128 + lg * 8;
  bf16x8 af[4];
#pragma unroll
  for (int s = 0; s < 4; ++s) {
    float v[8];
    if (valid) {
      float4 a = *reinterpret_cast<const float4*>(xrow + s * 32);
      float4 b = *reinterpret_cast<const float4*>(xrow + s * 32 + 4);
      v[0] = a.x; v[1] = a.y; v[2] = a.z; v[3] = a.w;
      v[4] = b.x; v[5] = b.y; v[6] = b.z; v[7] = b.w;
    } else {
#pragma unroll
      for (int j = 0; j < 8; ++j) v[j] = 0.f;
    }
    if constexpr (FUSE) {
#pragma unroll
      for (int j = 0; j < 8; ++j) {
        int f = lg * 8 + s * 32 + j;
        v[j] = fmaxf(v[j] * scsh[f] + scsh[128 + f], 0.f);
      }
    }
    union { unsigned short q[8]; bf16x8 bv; } pk;
#pragma unroll
    for (int j = 0; j < 8; ++j) pk.q[j] = f2b(v[j]);
    af[s] = pk.bv;
  }

  {  // stage WT -> LDS, XOR-swizzled
    const uint4* wg = reinterpret_cast<const uint4*>(WT);
    constexpr int C16 = NW * 16;
    for (int c = t; c < C16; c += 256) {
      int rw = c >> 4;
      unsigned byte = ((unsigned)c << 4) ^ (((unsigned)rw & 7u) << 4);
      *reinterpret_cast<uint4*>(smem + byte) = wg[c];
    }
  }
  __syncthreads();

  f32x4 acc[NT];
#pragma unroll
  for (int i = 0; i < NT; ++i) acc[i] = (f32x4){0.f, 0.f, 0.f, 0.f};

#pragma unroll
  for (int s = 0; s < 4; ++s) {
#pragma unroll
    for (int ct = 0; ct < NT; ++ct) {
      int rw = ct * 16 + ll;
      unsigned byte =
          (unsigned)rw * 256u + (((unsigned)(s * 64 + lg * 16)) ^
                                 (((unsigned)rw & 7u) << 4));
      uint4 u = *reinterpret_cast<const uint4*>(smem + byte);
      bf16x8 bf = __builtin_bit_cast(bf16x8, u);
      acc[ct] = __builtin_amdgcn_mfma_f32_16x16x32_bf16(af[s], bf, acc[ct], 0, 0, 0);
    }
  }

  __syncthreads();
  float* epi = reinterpret_cast<float*>(smem);
#pragma unroll
  for (int ct = 0; ct < NT; ++ct) {
    int col = ct * 16 + ll;
#pragma unroll
    for (int r = 0; r < 4; ++r) {
      epi[(w * 16 + lg * 4 + r) * EPR + col] = acc[ct][r];
    }
  }
  __syncthreads();

  constexpr int CPR = NW / 4;
  constexpr int TCH = DOUT / 4;
#pragma unroll
  for (int i = 0; i < NW / 16; ++i) {
    int c = i * 256 + t;
    int rw = c / CPR;
    int ch = c % CPR;
    int gr = blk * 64 + rw;
    if (gr >= n) continue;
    float4 v = *reinterpret_cast<const float4*>(epi + rw * EPR + ch * 4);
    if (ch < TCH) {
      ushort4 u;
      u.x = f2b(v.x); u.y = f2b(v.y); u.z = f2b(v.z); u.w = f2b(v.w);
      *reinterpret_cast<ushort4*>(T16 + (size_t)gr * DOUT + ch * 4) = u;
    } else {
      int cc = (ch - TCH) * 4;
      float4 bb = *reinterpret_cast<const float4*>(bias + cc);
      v.x += bb.x; v.y += bb.y; v.z += bb.z; v.w += bb.w;
      *reinterpret_cast<float4*>(H + (size_t)gr * DOUT + cc) = v;
    }
  }
}

// ---- pull-mode mean aggregation (32-lane groups, 8B loads, 8-deep unroll) ----
// fused BN-stats partials at stride 256
__global__ __launch_bounds__(256) void k_agg128(const int* __restrict__ rs,
                                                const int* __restrict__ csr,
                                                const unsigned short* __restrict__ T,
                                                float* __restrict__ H,
                                                float* __restrict__ partials, int n) {
  int t = threadIdx.x;
  int grp = t >> 5, lane = t & 31;
  int off = lane * 4;
  float4 s4 = make_float4(0.f, 0.f, 0.f, 0.f);
  float4 q4 = make_float4(0.f, 0.f, 0.f, 0.f);
  for (int g = blockIdx.x * 8 + grp; g < n; g += NBAGG * 8) {
    int e0 = rs[g], e1 = rs[g + 1];
    int d = e1 - e0;
    float inv = 1.0f / (float)(d > 1 ? d : 1);
    float4 a = make_float4(0.f, 0.f, 0.f, 0.f);
    int e = e0;
    for (; e + 8 <= e1; e += 8) {
      int s0 = csr[e],     s1 = csr[e + 1], s2 = csr[e + 2], s3 = csr[e + 3];
      int s5 = csr[e + 4], s6 = csr[e + 5], s7 = csr[e + 6], s8 = csr[e + 7];
      ushort4 v0 = *reinterpret_cast<const ushort4*>(T + (size_t)s0 * 128 + off);
      ushort4 v1 = *reinterpret_cast<const ushort4*>(T + (size_t)s1 * 128 + off);
      ushort4 v2 = *reinterpret_cast<const ushort4*>(T + (size_t)s2 * 128 + off);
      ushort4 v3 = *reinterpret_cast<const ushort4*>(T + (size_t)s3 * 128 + off);
      ushort4 v5 = *reinterpret_cast<const ushort4*>(T + (size_t)s5 * 128 + off);
      ushort4 v6 = *reinterpret_cast<const ushort4*>(T + (size_t)s6 * 128 + off);
      ushort4 v7 = *reinterpret_cast<const ushort4*>(T + (size_t)s7 * 128 + off);
      ushort4 v8 = *reinterpret_cast<const ushort4*>(T + (size_t)s8 * 128 + off);
      a.x += ((b2f(v0.x) + b2f(v1.x)) + (b2f(v2.x) + b2f(v3.x))) +
             ((b2f(v5.x) + b2f(v6.x)) + (b2f(v7.x) + b2f(v8.x)));
      a.y += ((b2f(v0.y) + b2f(v1.y)) + (b2f(v2.y) + b2f(v3.y))) +
             ((b2f(v5.y) + b2f(v6.y)) + (b2f(v7.y) + b2f(v8.y)));
      a.z += ((b2f(v0.z) + b2f(v1.z)) + (b2f(v2.z) + b2f(v3.z))) +
             ((b2f(v5.z) + b2f(v6.z)) + (b2f(v7.z) + b2f(v8.z)));
      a.w += ((b2f(v0.w) + b2f(v1.w)) + (b2f(v2.w) + b2f(v3.w))) +
             ((b2f(v5.w) + b2f(v6.w)) + (b2f(v7.w) + b2f(v8.w)));
    }
    for (; e < e1; ++e) {
      int s = csr[e];
      ushort4 v = *reinterpret_cast<const ushort4*>(T + (size_t)s * 128 + off);
      a.x += b2f(v.x); a.y += b2f(v.y); a.z += b2f(v.z); a.w += b2f(v.w);
    }
    float4* hp = reinterpret_cast<float4*>(H + (size_t)g * 128 + off);
    float4 h = *hp;
    h.x += a.x * inv; h.y += a.y * inv; h.z += a.z * inv; h.w += a.w * inv;
    *hp = h;
    s4.x += h.x; s4.y += h.y; s4.z += h.z; s4.w += h.w;
    q4.x += h.x * h.x; q4.y += h.y * h.y; q4.z += h.z * h.z; q4.w += h.w * h.w;
  }
  __shared__ float ls[128];
  __shared__ float lq[128];
  if (t < 128) { ls[t] = 0.f; lq[t] = 0.f; }
  __syncthreads();
  atomicAdd(&ls[off + 0], s4.x); atomicAdd(&ls[off + 1], s4.y);
  atomicAdd(&ls[off + 2], s4.z); atomicAdd(&ls[off + 3], s4.w);
  atomicAdd(&lq[off + 0], q4.x); atomicAdd(&lq[off + 1], q4.y);
  atomicAdd(&lq[off + 2], q4.z); atomicAdd(&lq[off + 3], q4.w);
  __syncthreads();
  partials[(size_t)blockIdx.x * 256 + t] = (t < 128) ? ls[t] : lq[t - 128];
}

__global__ __launch_bounds__(256) void k_agg64(const int* __restrict__ rs,
                                               const int* __restrict__ csr,
                                               const unsigned short* __restrict__ T,
                                               float* __restrict__ H,
                                               float* __restrict__ partials, int n) {
  int t = threadIdx.x;
  int grp = t >> 4, lane = t & 15;
  int off = lane * 4;
  float4 s4 = make_float4(0.f, 0.f, 0.f, 0.f);
  float4 q4 = make_float4(0.f, 0.f, 0.f, 0.f);
  for (int g = blockIdx.x * 16 + grp; g < n; g += NBAGG * 16) {
    int e0 = rs[g], e1 = rs[g + 1];
    int d = e1 - e0;
    float inv = 1.0f / (float)(d > 1 ? d : 1);
    float4 a = make_float4(0.f, 0.f, 0.f, 0.f);
    int e = e0;
    for (; e + 8 <= e1; e += 8) {
      int s0 = csr[e],     s1 = csr[e + 1], s2 = csr[e + 2], s3 = csr[e + 3];
      int s5 = csr[e + 4], s6 = csr[e + 5], s7 = csr[e + 6], s8 = csr[e + 7];
      ushort4 v0 = *reinterpret_cast<const ushort4*>(T + (size_t)s0 * 64 + off);
      ushort4 v1 = *reinterpret_cast<const ushort4*>(T + (size_t)s1 * 64 + off);
      ushort4 v2 = *reinterpret_cast<const ushort4*>(T + (size_t)s2 * 64 + off);
      ushort4 v3 = *reinterpret_cast<const ushort4*>(T + (size_t)s3 * 64 + off);
      ushort4 v5 = *reinterpret_cast<const ushort4*>(T + (size_t)s5 * 64 + off);
      ushort4 v6 = *reinterpret_cast<const ushort4*>(T + (size_t)s6 * 64 + off);
      ushort4 v7 = *reinterpret_cast<const ushort4*>(T + (size_t)s7 * 64 + off);
      ushort4 v8 = *reinterpret_cast<const ushort4*>(T + (size_t)s8 * 64 + off);
      a.x += ((b2f(v0.x) + b2f(v1.x)) + (b2f(v2.x) + b2f(v3.x))) +
             ((b2f(v5.x) + b2f(v6.x)) + (b2f(v7.x) + b2f(v8.x)));
      a.y += ((b2f(v0.y) + b2f(v1.y)) + (b2f(v2.y) + b2f(v3.y))) +
             ((b2f(v5.y) + b2f(v6.y)) + (b2f(v7.y) + b2f(v8.y)));
      a.z += ((b2f(v0.z) + b2f(v1.z)) + (b2f(v2.z) + b2f(v3.z))) +
             ((b2f(v5.z) + b2f(v6.z)) + (b2f(v7.z) + b2f(v8.z)));
      a.w += ((b2f(v0.w) + b2f(v1.w)) + (b2f(v2.w) + b2f(v3.w))) +
             ((b2f(v5.w) + b2f(v6.w)) + (b2f(v7.w) + b2f(v8.w)));
    }
    for (; e < e1; ++e) {
      int s = csr[e];
      ushort4 v = *reinterpret_cast<const ushort4*>(T + (size_t)s * 64 + off);
      a.x += b2f(v.x); a.y += b2f(v.y); a.z += b2f(v.z); a.w += b2f(v.w);
    }
    float4* hp = reinterpret_cast<float4*>(H + (size_t)g * 64 + off);
    float4 h = *hp;
    h.x += a.x * inv; h.y += a.y * inv; h.z += a.z * inv; h.w += a.w * inv;
    *hp = h;
    s4.x += h.x; s4.y += h.y; s4.z += h.z; s4.w += h.w;
    q4.x += h.x * h.x; q4.y += h.y * h.y; q4.z += h.z * h.z; q4.w += h.w * h.w;
  }
  __shared__ float ls[64];
  __shared__ float lq[64];
  if (t < 64) { ls[t] = 0.f; lq[t] = 0.f; }
  __syncthreads();
  atomicAdd(&ls[off + 0], s4.x); atomicAdd(&ls[off + 1], s4.y);
  atomicAdd(&ls[off + 2], s4.z); atomicAdd(&ls[off + 3], s4.w);
  atomicAdd(&lq[off + 0], q4.x); atomicAdd(&lq[off + 1], q4.y);
  atomicAdd(&lq[off + 2], q4.z); atomicAdd(&lq[off + 3], q4.w);
  __syncthreads();
  if (t < 128)
    partials[(size_t)blockIdx.x * 256 + t] = (t < 64) ? ls[t] : lq[t - 64];
}

// reduce partials (stride 256) -> bns; one wave per feature
__global__ __launch_bounds__(64) void k_red(const float* __restrict__ partials,
                                            float* __restrict__ bns) {
  int f = blockIdx.x;
  int j = threadIdx.x;
  float acc = 0.f;
  for (int b = j; b < NBAGG; b += 64) acc += partials[(size_t)b * 256 + f];
#pragma unroll
  for (int off = 32; off > 0; off >>= 1) acc += __shfl_down(acc, off);
  if (j == 0) bns[f] = acc;
}

// final norm (layer 2 only) -> d_out (f32)
template <int DOUT, bool RELU>
__global__ __launch_bounds__(256) void k_bn_norm(const float* __restrict__ H,
                                                 const float* __restrict__ sums,
                                                 const float* __restrict__ gamma,
                                                 const float* __restrict__ beta,
                                                 float* __restrict__ O, int n) {
  float invn = 1.0f / (float)n;
  int total4 = n * (DOUT / 4);
  for (int idx = blockIdx.x * blockDim.x + threadIdx.x; idx < total4;
       idx += gridDim.x * blockDim.x) {
    int f0 = (idx % (DOUT / 4)) * 4;
    float4 h = reinterpret_cast<const float4*>(H)[idx];
    float hv[4] = {h.x, h.y, h.z, h.w};
    float o[4];
#pragma unroll
    for (int c = 0; c < 4; ++c) {
      int f = f0 + c;
      float m = sums[f] * invn;
      float var = sums[DOUT + f] * invn - m * m;
      float sc = gamma[f] * rsqrtf(var + 1e-5f);
      float sh = beta[f] - m * sc;
      float v = hv[c] * sc + sh;
      if (RELU) v = fmaxf(v, 0.f);
      o[c] = v;
    }
    reinterpret_cast<float4*>(O)[idx] = make_float4(o[0], o[1], o[2], o[3]);
  }
}

// ---------------- host ----------------
extern "C" void kernel_launch(void* const* d_in, const int* in_sizes, int n_in,
                              void* d_out, int out_size, void* d_ws, size_t ws_size,
                              hipStream_t stream) {
  const float* x = (const float*)d_in[0];
  const int* ei = (const int*)d_in[1];
  int n = in_sizes[0] / 128;
  int e = in_sizes[1] / 2;
  int npad = (n + 63) & ~63;
  int nbuk = (n + 511) >> 9;
  const int* src = ei;
  const int* dst = ei + e;

  char* p = (char*)d_ws;
  auto carve = [&](size_t bytes) {
    char* r = p;
    p += (bytes + 255) & ~(size_t)255;
    return r;
  };
  int* deg = (int*)carve((size_t)n * 4);
  int* rs = (int*)carve((size_t)(n + 1) * 4);
  int* bcnt = (int*)carve(1024);
  int* bsum = (int*)carve(4096);
  int* boff = (int*)carve(4096);
  float* bns = (float*)carve(1024);
  unsigned short* WTall = (unsigned short*)carve((size_t)81920 * 2);
  float* partials = (float*)carve((size_t)NBAGG * 256 * 4);
  unsigned int* barr = (unsigned int*)carve((size_t)nbuk * BCAP * 4);
  int* csr = (int*)carve((size_t)e * 4);
  unsigned short* T16 = (unsigned short*)carve((size_t)n * 128 * 2);
  float* Ha = (float*)carve((size_t)n * 128 * 4);
  float* Hb = (float*)carve((size_t)n * 128 * 4);

  const float* Wl0 = (const float*)d_in[2];
  const float* Wr0 = (const float*)d_in[3];
  const float* b0 = (const float*)d_in[4];
  const float* gm0 = (const float*)d_in[5];
  const float* bt0 = (const float*)d_in[6];
  const float* Wl1 = (const float*)d_in[7];
  const float* Wr1 = (const float*)d_in[8];
  const float* b1 = (const float*)d_in[9];
  const float* gm1 = (const float*)d_in[10];
  const float* bt1 = (const float*)d_in[11];
  const float* Wl2 = (const float*)d_in[12];
  const float* Wr2 = (const float*)d_in[13];
  const float* b2 = (const float*)d_in[14];
  const float* gm2 = (const float*)d_in[15];
  const float* bt2 = (const float*)d_in[16];

  // ---- CSR build ----
  hipMemsetAsync(bcnt, 0, 1024, stream);
  int gA = (e + 2047) / 2048;
  int nb1 = (n + 255) / 256;
  k_part<<<gA, 256, 0, stream>>>(src, dst, bcnt, barr, e, nbuk);
  k_bdeg<<<nbuk, 512, 0, stream>>>(bcnt, barr, deg, n);
  k_scan1<<<nb1, 256, 0, stream>>>(deg, rs, bsum, n);
  k_scan2<<<1, 512, 0, stream>>>(bsum, boff, nb1);
  k_scan3<<<nb1, 256, 0, stream>>>(rs, boff, n, e);
  k_place<<<nbuk, 512, 0, stream>>>(bcnt, barr, rs, csr, n);

  k_wt_all<<<320, 256, 0, stream>>>(Wl0, Wr0, Wl1, Wr1, Wl2, Wr2, WTall);

  int gg = npad / 64;

  // layer 0
  k_gemm<256, false><<<gg, 256, 0, stream>>>(x, WTall, b0, bns, gm0, bt0, T16, Ha, n);
  k_agg128<<<NBAGG, 256, 0, stream>>>(rs, csr, T16, Ha, partials, n);
  k_red<<<256, 64, 0, stream>>>(partials, bns);
  // layer 1
  k_gemm<256, true><<<gg, 256, 0, stream>>>(Ha, WTall + 32768, b1, bns, gm0, bt0, T16, Hb, n);
  k_agg128<<<NBAGG, 256, 0, stream>>>(rs, csr, T16, Hb, partials, n);
  k_red<<<256, 64, 0, stream>>>(partials, bns);
  // layer 2
  k_gemm<128, true><<<gg, 256, 0, stream>>>(Hb, WTall + 65536, b2, bns, gm1, bt1, T16, Ha, n);
  k_agg64<<<NBAGG, 256, 0, stream>>>(rs, csr, T16, Ha, partials, n);
  k_red<<<128, 64, 0, stream>>>(partials, bns);
  int total4 = n * 64 / 4;
  int gn = (total4 + 255) / 256;
  if (gn > 2048) gn = 2048;
  k_bn_norm<64, false><<<gn, 256, 0, stream>>>(Ha, bns, gm2, bt2, (float*)d_out, n);
}